// Round 11
// baseline (237.284 us; speedup 1.0000x reference)
//
#include <hip/hip_runtime.h>
#include <hip/hip_bf16.h>

#define NN 4096
#define CAP 128    // compacted nnz cap per row (mean 41, +8sigma ~ 92)
#define CAPV 256   // chunked slot region: 16 chunks x 16 slots per row
#define KS 8       // k-splits for P-GEMM
#define PGB 512    // pgemm blocks (256-thr, 4 wave-tiles each) at grid head

typedef __attribute__((ext_vector_type(8))) short bf16x8;
typedef __attribute__((ext_vector_type(4))) float f32x4;

__device__ __forceinline__ float lrelu(float v) { return v >= 0.f ? v : 0.2f * v; }

// fp32 -> bf16 bits, round-to-nearest-even (inputs are finite)
__device__ __forceinline__ ushort f2bu(float f) {
    unsigned u = __float_as_uint(f);
    return (ushort)((u + 0x7FFFu + ((u >> 16) & 1u)) >> 16);
}

// ---------------------------------------------------------------------------
// K1: xwA1=x@W1[0], xwB1=x@W1[1], xwA2=x@W2[0], xwB2=x@W2[1], v0=x@W0,
//     a/b attention vectors, Bt = (x@W0)^T as bf16 for the P-GEMM.
// ---------------------------------------------------------------------------
__global__ __launch_bounds__(256) void k_prep(
    const float* __restrict__ x,
    const float* __restrict__ W1, const float* __restrict__ W2,
    const float* __restrict__ W0,
    const float* __restrict__ att1, const float* __restrict__ att2,
    float* __restrict__ xwA1, float* __restrict__ xwB1,
    float* __restrict__ xwA2, float* __restrict__ xwB2,
    float* __restrict__ a1, float* __restrict__ b1,
    float* __restrict__ a2, float* __restrict__ b2,
    __hip_bfloat16* __restrict__ Bt)
{
    __shared__ float wl[5120];   // W1(2048) W2(2048) W0(1024)
    __shared__ float xs[256];    // 8 rows x 32
    const int t = threadIdx.x;
    for (int i = t; i < 2048; i += 256) { wl[i] = W1[i]; wl[2048 + i] = W2[i]; }
    for (int i = t; i < 1024; i += 256) wl[4096 + i] = W0[i];
    const int rowBase = blockIdx.x * 8;
    xs[t] = x[rowBase * 32 + t];
    __syncthreads();

    const int o = t & 31, r = t >> 5;
    const int row = rowBase + r;
    const float* xr = &xs[r * 32];
    float vA1 = 0.f, vB1 = 0.f, vA2 = 0.f, vB2 = 0.f, v0 = 0.f;
#pragma unroll
    for (int f = 0; f < 32; ++f) {
        const float xv = xr[f];
        vA1 += xv * wl[f * 32 + o];
        vB1 += xv * wl[1024 + f * 32 + o];
        vA2 += xv * wl[2048 + f * 32 + o];
        vB2 += xv * wl[3072 + f * 32 + o];
        v0  += xv * wl[4096 + f * 32 + o];
    }
    xwA1[row * 32 + o] = vA1;
    xwB1[row * 32 + o] = vB1;
    xwA2[row * 32 + o] = vA2;
    xwB2[row * 32 + o] = vB2;
    ((ushort*)Bt)[(size_t)o * NN + row] = f2bu(v0);

    float pa1 = vA1 * att1[o]      + vB1 * att1[32 + o];
    float pb1 = vA1 * att1[64 + o] + vB1 * att1[96 + o];
    float pa2 = vA2 * att2[o]      + vB2 * att2[32 + o];
    float pb2 = vA2 * att2[64 + o] + vB2 * att2[96 + o];
#pragma unroll
    for (int m = 1; m <= 16; m <<= 1) {
        pa1 += __shfl_xor(pa1, m); pb1 += __shfl_xor(pb1, m);
        pa2 += __shfl_xor(pa2, m); pb2 += __shfl_xor(pb2, m);
    }
    if (o == 0) { a1[row] = pa1; b1[row] = pb1; a2[row] = pa2; b2[row] = pb2; }
}

// ---------------------------------------------------------------------------
// K2 (k_stream): fill/copy-shaped extraction + pgemm.
//   blocks [0, PGB)   : pgemm body (per-wave MFMA, verified r4-r10), 4/block.
//   blocks [PGB, ...) : wave per (row,branch). Stream the 16 KB row as 16
//     1-KB chunks (wave-uniform row per chunk). Per chunk: ballot-prefix
//     assigns slots in a FIXED 16-slot region (chunk c -> csr slots
//     [c*16, c*16+16)) -- no atomics, no LDS, no barriers, no cross-chunk
//     dependency; stores fire-and-forget. Sentinels (0, 0.0f) fill unused
//     slots. val==0.0f <=> masked (matches reference's L != 0 test).
// ---------------------------------------------------------------------------
__global__ __launch_bounds__(256) void k_stream(
    const float* __restrict__ Ld, const float* __restrict__ Lu,
    int2* __restrict__ csrv,
    const float* __restrict__ P, const ushort* __restrict__ Bt,
    float* __restrict__ partial)
{
    const int bid = blockIdx.x;
    const int t = threadIdx.x;
    const int lane = t & 63, w = t >> 6;

    if (bid < PGB) {
        // ---------------- pgemm body (per-wave, verified r4-r10) ---------
        const int gw = bid * 4 + w;            // 0..2047
        const int mt = gw & 255;               // m-tile (16 rows)
        const int ks = gw >> 8;                // k-split 0..7
        const int m0 = mt * 16;
        const int r  = lane & 15;              // A row / B col within tile
        const int kq = lane >> 4;              // 8-k subchunk 0..3

        const float*  pa  = P  + (size_t)(m0 + r) * NN + ks * 512 + kq * 8;
        const ushort* pb0 = Bt + (size_t)r        * NN + ks * 512 + kq * 8;
        const ushort* pb1 = Bt + (size_t)(16 + r) * NN + ks * 512 + kq * 8;

        f32x4 acc0 = {0.f, 0.f, 0.f, 0.f};
        f32x4 acc1 = {0.f, 0.f, 0.f, 0.f};

#pragma unroll 4
        for (int kk = 0; kk < 16; ++kk) {
            const float4 a0  = *(const float4*)(pa + kk * 32);
            const float4 a1v = *(const float4*)(pa + kk * 32 + 4);
            const bf16x8 b0  = *(const bf16x8*)(pb0 + kk * 32);
            const bf16x8 b1v = *(const bf16x8*)(pb1 + kk * 32);
            bf16x8 a;
            a[0] = (short)f2bu(a0.x);  a[1] = (short)f2bu(a0.y);
            a[2] = (short)f2bu(a0.z);  a[3] = (short)f2bu(a0.w);
            a[4] = (short)f2bu(a1v.x); a[5] = (short)f2bu(a1v.y);
            a[6] = (short)f2bu(a1v.z); a[7] = (short)f2bu(a1v.w);
            acc0 = __builtin_amdgcn_mfma_f32_16x16x32_bf16(a, b0, acc0, 0, 0, 0);
            acc1 = __builtin_amdgcn_mfma_f32_16x16x32_bf16(a, b1v, acc1, 0, 0, 0);
        }

        float* out = partial + ((size_t)ks * NN + m0 + kq * 4) * 32;
#pragma unroll
        for (int rr = 0; rr < 4; ++rr) {
            out[rr * 32 + r]      = acc0[rr];
            out[rr * 32 + 16 + r] = acc1[rr];
        }
        return;
    }

    // ---------------- stream body: wave per (row, branch) ----------------
    const int su = (bid - PGB) * 4 + w;        // 0..8191 == br*NN + row
    const int br = su >> 12, row = su & (NN - 1);
    const float4* L4 = (const float4*)((br ? Lu : Ld) + (size_t)row * NN);
    int2* csrB = csrv + (size_t)su * CAPV;
    const unsigned long long lt = (1ull << lane) - 1ull;

#pragma unroll
    for (int h = 0; h < 2; ++h) {
        float4 v[8];
#pragma unroll
        for (int j = 0; j < 8; ++j) v[j] = L4[(h * 8 + j) * 64 + lane];
#pragma unroll
        for (int j = 0; j < 8; ++j) {
            const int c = h * 8 + j;
            const float vx = v[j].x, vy = v[j].y, vz = v[j].z, vw = v[j].w;
            const unsigned long long m0 = __ballot(vx != 0.f);
            const unsigned long long m1 = __ballot(vy != 0.f);
            const unsigned long long m2 = __ballot(vz != 0.f);
            const unsigned long long m3 = __ballot(vw != 0.f);
            const int p0 = __popcll(m0), p1 = __popcll(m1), p2 = __popcll(m2);
            const int n  = p0 + p1 + p2 + __popcll(m3);
            const int c0 = c * 256 + lane * 4;   // element index within row
            int2* cb = csrB + c * 16;
            int s;
            s = __popcll(m0 & lt);
            if (vx != 0.f && s < 16) { int2 e; e.x = c0;     e.y = __float_as_int(vx); cb[s] = e; }
            s = p0 + __popcll(m1 & lt);
            if (vy != 0.f && s < 16) { int2 e; e.x = c0 + 1; e.y = __float_as_int(vy); cb[s] = e; }
            s = p0 + p1 + __popcll(m2 & lt);
            if (vz != 0.f && s < 16) { int2 e; e.x = c0 + 2; e.y = __float_as_int(vz); cb[s] = e; }
            s = p0 + p1 + p2 + __popcll(m3 & lt);
            if (vw != 0.f && s < 16) { int2 e; e.x = c0 + 3; e.y = __float_as_int(vw); cb[s] = e; }
            if (lane >= n && lane < 16) { int2 z; z.x = 0; z.y = 0; cb[lane] = z; }
        }
    }
}

// ---------------------------------------------------------------------------
// K3 (k_soft): wave per (row,branch) on COMPACTED data (~2 KB/unit).
// Load the 256 chunked slots, wave-local ballot-compact (val!=0) into a
// wave-private LDS list, then the r2-VERIFIED body: wave-shuffle softmax,
// write normalized+32-padded weights back to csrv[0..cp32), cnt, and the
// fused y-gather u = xwA + sum(raw * xwB[idx]).
// ---------------------------------------------------------------------------
__global__ __launch_bounds__(256) void k_soft(
    const float* __restrict__ xwB1, const float* __restrict__ xwB2,
    const float* __restrict__ xwA1, const float* __restrict__ xwA2,
    const float* __restrict__ a1, const float* __restrict__ b1,
    const float* __restrict__ a2, const float* __restrict__ b2,
    int2* __restrict__ csrv, int* __restrict__ cntArr,
    float* __restrict__ u1, float* __restrict__ u2)
{
    __shared__ int2 slist_all[4][CAP];
    const int t = threadIdx.x;
    const int lane = t & 63, w = t >> 6;
    const int su = blockIdx.x * 4 + w;         // 0..8191
    const int br = su >> 12, row = su & (NN - 1);
    const float* xwB = br ? xwB2 : xwB1;
    const float* xwA = br ? xwA2 : xwA1;
    const float* aA  = br ? a2 : a1;
    const float* bA  = br ? b2 : b1;
    int2* csrB = csrv + (size_t)su * CAPV;
    float* u   = br ? u2 : u1;
    int2* slist = slist_all[w];
    const unsigned long long lt = (1ull << lane) - 1ull;

    // load all 256 chunked slots: 4 int2 per lane
    int2 e[4];
#pragma unroll
    for (int k = 0; k < 4; ++k) e[k] = csrB[k * 64 + lane];

    // wave-local compaction into slist
    int base = 0;
#pragma unroll
    for (int k = 0; k < 4; ++k) {
        const unsigned long long mk = __ballot(e[k].y != 0);
        const int s = base + __popcll(mk & lt);
        if (e[k].y != 0 && s < CAP) slist[s] = e[k];
        base += __popcll(mk);
    }
    const int cnt  = min(base, CAP);
    const int cp32 = min((cnt + 31) & ~31, CAP);   // 32-padding (accum matches)
    const int ps = cnt + lane;
    if (ps < cp32) { int2 z; z.x = 0; z.y = 0; slist[ps] = z; }

    // same-wave LDS RAW fence (r2-verified pattern)
    asm volatile("s_waitcnt lgkmcnt(0)" ::: "memory");
    __builtin_amdgcn_sched_barrier(0);

    // --- wave-shuffle softmax: lane owns slots lane, lane+64 (r2 body) ---
    const float ai = aA[row];
    int iA = 0, iB = 0;
    float eA = -1e30f, eB = -1e30f;
    if (lane < cnt)      { iA = slist[lane].x;      eA = lrelu(ai + bA[iA]); }
    if (64 + lane < cnt) { iB = slist[64 + lane].x; eB = lrelu(ai + bA[iB]); }
    float mx = fmaxf(eA, eB);
#pragma unroll
    for (int mm = 1; mm <= 32; mm <<= 1) mx = fmaxf(mx, __shfl_xor(mx, mm));
    const float w0 = (lane < cnt)      ? __expf(eA - mx) : 0.f;
    const float w1 = (64 + lane < cnt) ? __expf(eB - mx) : 0.f;
    float ss = w0 + w1;
#pragma unroll
    for (int mm = 1; mm <= 32; mm <<= 1) ss += __shfl_xor(ss, mm);
    const float inv = (cnt > 0) ? 1.f / ss : 0.f;
    if (lane < cp32)      { int2 eo; eo.x = iA; eo.y = __float_as_int(w0 * inv); csrB[lane] = eo; }
    if (64 + lane < cp32) { int2 eo; eo.x = iB; eo.y = __float_as_int(w1 * inv); csrB[64 + lane] = eo; }
    if (lane == 0) cntArr[su] = cnt;

    // --- fused y-gather (raw values in slist): 2 groups of 32 (r2 body) ---
    const int o = lane & 31, g = lane >> 5;
    float acc = 0.f;
    for (int s0 = 0; s0 < cp32; s0 += 8) {
        float vv[4], uu[4];
#pragma unroll
        for (int q = 0; q < 4; ++q) {
            const int2 ee = slist[s0 + 2 * q + g];
            vv[q] = __int_as_float(ee.y);
            uu[q] = xwB[(size_t)ee.x * 32 + o];
        }
#pragma unroll
        for (int q = 0; q < 4; ++q) acc += vv[q] * uu[q];
    }
    acc += __shfl_xor(acc, 32);
    if (lane < 32) u[(size_t)row * 32 + o] = acc + xwA[(size_t)row * 32 + o];
}

// ---------------------------------------------------------------------------
// K4 (k_accum): wave per row. Weighted gather of U for both branches
// (weights pre-normalized, 32-padded with sentinels, stride CAPV), KS
// partials hoisted to the top; 16-slot chunks per wave (8 loads in flight).
// ---------------------------------------------------------------------------
__global__ __launch_bounds__(256) void k_accum(
    const int2* __restrict__ csrv, const int* __restrict__ cntArr,
    const float* __restrict__ u1, const float* __restrict__ u2,
    const float* __restrict__ partial, float* __restrict__ outp)
{
    __shared__ int2 sle[4][2 * CAP];
    const int w = threadIdx.x >> 6, lane = threadIdx.x & 63;
    const int row = blockIdx.x * 4 + w;
    const int o = lane & 31, g = lane >> 5;
    int2* se = sle[w];

    // KS-partial fold first: 8 independent coalesced loads, issued early
    float total = 0.f;
#pragma unroll
    for (int p = 0; p < KS; ++p)
        total += partial[(size_t)p * NN * 32 + (size_t)row * 32 + o];

    int cp[2];
#pragma unroll
    for (int br = 0; br < 2; ++br) {
        const int cnt = cntArr[br * NN + row];
        cp[br] = min((cnt + 31) & ~31, CAP);     // 32-padding (soft matches)
        const int2* ci = csrv + (size_t)(br * NN + row) * CAPV;
        if (lane < cp[br])      se[br * CAP + lane]      = ci[lane];
        if (lane + 64 < cp[br]) se[br * CAP + lane + 64] = ci[lane + 64];
    }
    // wave-private LDS segment; same-wave ordering

#pragma unroll
    for (int br = 0; br < 2; ++br) {
        const float* U = br ? u2 : u1;
        float acc = 0.f;
        const int nb = cp[br] >> 4;              // 16-slot chunks
        for (int j = 0; j < nb; ++j) {
            float wv[8], uv[8];
#pragma unroll
            for (int q = 0; q < 8; ++q) {
                const int2 e = se[br * CAP + 16 * j + 2 * q + g];
                wv[q] = __int_as_float(e.y);
                uv[q] = U[(size_t)e.x * 32 + o];
            }
#pragma unroll
            for (int q = 0; q < 8; ++q) acc += wv[q] * uv[q];
        }
        acc += __shfl_xor(acc, 32);
        total += acc;
    }

    if (lane < 32) outp[(size_t)row * 32 + o] = total;
}

extern "C" void kernel_launch(void* const* d_in, const int* in_sizes, int n_in,
                              void* d_out, int out_size, void* d_ws, size_t ws_size,
                              hipStream_t stream) {
    (void)in_sizes; (void)n_in; (void)out_size; (void)ws_size;
    const float* x    = (const float*)d_in[0];
    const float* Ld   = (const float*)d_in[1];
    const float* Lu   = (const float*)d_in[2];
    const float* P    = (const float*)d_in[3];
    const float* W1   = (const float*)d_in[4];
    const float* W2   = (const float*)d_in[5];
    const float* W0   = (const float*)d_in[6];
    const float* att1 = (const float*)d_in[7];
    const float* att2 = (const float*)d_in[8];

    float* ws = (float*)d_ws;
    float* xwA1 = ws;                 // 131072 each
    float* xwB1 = ws + 131072;
    float* xwA2 = ws + 262144;
    float* xwB2 = ws + 393216;
    float* u1   = ws + 524288;        // xwA + L@xwB (fused)
    float* u2   = ws + 655360;
    float* a1   = ws + 786432;        // 4096 each
    float* b1   = ws + 790528;
    float* a2   = ws + 794624;
    float* b2   = ws + 798720;
    float* partial = ws + 802816;           // KS*131072 floats = 4 MB
    __hip_bfloat16* Bt = (__hip_bfloat16*)(ws + 1851392);   // 131072 bf16
    int2* csrv = (int2*)(ws + 1916928);     // 2*4096*256 int2 = 16 MB
    int*  cnt  = (int*)(ws + 6111232);      // 8192 ints

    k_prep<<<512, 256, 0, stream>>>(x, W1, W2, W0, att1, att2,
                                    xwA1, xwB1, xwA2, xwB2, a1, b1, a2, b2, Bt);
    k_stream<<<PGB + 2048, 256, 0, stream>>>(Ld, Lu, csrv,
                                             P, (const ushort*)Bt, partial);
    k_soft<<<2048, 256, 0, stream>>>(xwB1, xwB2, xwA1, xwA2,
                                     a1, b1, a2, b2, csrv, cnt, u1, u2);
    k_accum<<<NN / 4, 256, 0, stream>>>(csrv, cnt, u1, u2, partial,
                                        (float*)d_out);
}

// Round 12
// 222.921 us; speedup vs baseline: 1.0644x; 1.0644x over previous
//
#include <hip/hip_runtime.h>
#include <hip/hip_bf16.h>

#define NN 4096
#define CAP 128   // max nnz per row tracked (binomial mean 41, sd 6.4)
#define KS 8      // k-splits for P-GEMM
#define PGB 1024  // pgemm blocks (128-thr, 2 wave-tiles each) at grid head

typedef __attribute__((ext_vector_type(8))) short bf16x8;
typedef __attribute__((ext_vector_type(4))) float f32x4;

// global -> LDS direct copy, 16 B per lane (gfx950). LDS dest is wave-uniform
// base (+ lane*16 applied by HW); global src is per-lane. Verified r9.
typedef __attribute__((address_space(1))) const void gas_t;
typedef __attribute__((address_space(3))) void las_t;
#define GLOAD_LDS16(gsrc, ldst) \
    __builtin_amdgcn_global_load_lds((gas_t*)(gsrc), (las_t*)(ldst), 16, 0, 0)

__device__ __forceinline__ float lrelu(float v) { return v >= 0.f ? v : 0.2f * v; }

// fp32 -> bf16 bits, round-to-nearest-even (inputs are finite)
__device__ __forceinline__ ushort f2bu(float f) {
    unsigned u = __float_as_uint(f);
    return (ushort)((u + 0x7FFFu + ((u >> 16) & 1u)) >> 16);
}

// ---------------------------------------------------------------------------
// K1: xwA1=x@W1[0], xwB1=x@W1[1], xwA2=x@W2[0], xwB2=x@W2[1], v0=x@W0,
//     a/b attention vectors, Bt = (x@W0)^T as bf16 for the P-GEMM.
// ---------------------------------------------------------------------------
__global__ __launch_bounds__(256) void k_prep(
    const float* __restrict__ x,
    const float* __restrict__ W1, const float* __restrict__ W2,
    const float* __restrict__ W0,
    const float* __restrict__ att1, const float* __restrict__ att2,
    float* __restrict__ xwA1, float* __restrict__ xwB1,
    float* __restrict__ xwA2, float* __restrict__ xwB2,
    float* __restrict__ a1, float* __restrict__ b1,
    float* __restrict__ a2, float* __restrict__ b2,
    __hip_bfloat16* __restrict__ Bt)
{
    __shared__ float wl[5120];   // W1(2048) W2(2048) W0(1024)
    __shared__ float xs[256];    // 8 rows x 32
    const int t = threadIdx.x;
    for (int i = t; i < 2048; i += 256) { wl[i] = W1[i]; wl[2048 + i] = W2[i]; }
    for (int i = t; i < 1024; i += 256) wl[4096 + i] = W0[i];
    const int rowBase = blockIdx.x * 8;
    xs[t] = x[rowBase * 32 + t];
    __syncthreads();

    const int o = t & 31, r = t >> 5;
    const int row = rowBase + r;
    const float* xr = &xs[r * 32];
    float vA1 = 0.f, vB1 = 0.f, vA2 = 0.f, vB2 = 0.f, v0 = 0.f;
#pragma unroll
    for (int f = 0; f < 32; ++f) {
        const float xv = xr[f];
        vA1 += xv * wl[f * 32 + o];
        vB1 += xv * wl[1024 + f * 32 + o];
        vA2 += xv * wl[2048 + f * 32 + o];
        vB2 += xv * wl[3072 + f * 32 + o];
        v0  += xv * wl[4096 + f * 32 + o];
    }
    xwA1[row * 32 + o] = vA1;
    xwB1[row * 32 + o] = vB1;
    xwA2[row * 32 + o] = vA2;
    xwB2[row * 32 + o] = vB2;
    ((ushort*)Bt)[(size_t)o * NN + row] = f2bu(v0);

    float pa1 = vA1 * att1[o]      + vB1 * att1[32 + o];
    float pb1 = vA1 * att1[64 + o] + vB1 * att1[96 + o];
    float pa2 = vA2 * att2[o]      + vB2 * att2[32 + o];
    float pb2 = vA2 * att2[64 + o] + vB2 * att2[96 + o];
#pragma unroll
    for (int m = 1; m <= 16; m <<= 1) {
        pa1 += __shfl_xor(pa1, m); pb1 += __shfl_xor(pb1, m);
        pa2 += __shfl_xor(pa2, m); pb2 += __shfl_xor(pb2, m);
    }
    if (o == 0) { a1[row] = pa1; b1[row] = pb1; a2[row] = pa2; b2[row] = pb2; }
}

// ---------------------------------------------------------------------------
// K2 (k_fused): heterogeneous dispatch, 128-thread blocks. BYTE-IDENTICAL to
// the r9 best (220.9 us): pgemm head blocks + scan via global_load_lds
// staging, atomic compaction, wave-shuffle softmax, fused y-gather.
// ---------------------------------------------------------------------------
__global__ __launch_bounds__(128) void k_fused(
    const float* __restrict__ Ld, const float* __restrict__ Lu,
    const float* __restrict__ xwB1, const float* __restrict__ xwB2,
    const float* __restrict__ xwA1, const float* __restrict__ xwA2,
    const float* __restrict__ a1, const float* __restrict__ b1,
    const float* __restrict__ a2, const float* __restrict__ b2,
    int2* __restrict__ csrv, int* __restrict__ cntArr,
    float* __restrict__ u1, float* __restrict__ u2,
    const float* __restrict__ P, const ushort* __restrict__ Bt,
    float* __restrict__ partial)
{
    __shared__ float4 lrow[NN / 4];   // 16 KB staged row
    __shared__ int   sidx[CAP];
    __shared__ float sval[CAP];
    __shared__ float red[128];
    __shared__ float rpart[4];
    __shared__ int   lcnt;

    const int bid = blockIdx.x;
    const int t = threadIdx.x;
    const int lane = t & 63, w = t >> 6;      // w in {0,1}

    if (bid < PGB) {
        // ---------------- pgemm body (per-wave, verified r4-r9) ----------
        const int gw = bid * 2 + w;            // 0..2047
        const int mt = gw & 255;               // m-tile (16 rows)
        const int ks = gw >> 8;                // k-split 0..7
        const int m0 = mt * 16;
        const int r  = lane & 15;              // A row / B col within tile
        const int kq = lane >> 4;              // 8-k subchunk 0..3

        const float*  pa  = P  + (size_t)(m0 + r) * NN + ks * 512 + kq * 8;
        const ushort* pb0 = Bt + (size_t)r        * NN + ks * 512 + kq * 8;
        const ushort* pb1 = Bt + (size_t)(16 + r) * NN + ks * 512 + kq * 8;

        f32x4 acc0 = {0.f, 0.f, 0.f, 0.f};
        f32x4 acc1 = {0.f, 0.f, 0.f, 0.f};

#pragma unroll 4
        for (int kk = 0; kk < 16; ++kk) {
            const float4 a0  = *(const float4*)(pa + kk * 32);
            const float4 a1v = *(const float4*)(pa + kk * 32 + 4);
            const bf16x8 b0  = *(const bf16x8*)(pb0 + kk * 32);
            const bf16x8 b1v = *(const bf16x8*)(pb1 + kk * 32);
            bf16x8 a;
            a[0] = (short)f2bu(a0.x);  a[1] = (short)f2bu(a0.y);
            a[2] = (short)f2bu(a0.z);  a[3] = (short)f2bu(a0.w);
            a[4] = (short)f2bu(a1v.x); a[5] = (short)f2bu(a1v.y);
            a[6] = (short)f2bu(a1v.z); a[7] = (short)f2bu(a1v.w);
            acc0 = __builtin_amdgcn_mfma_f32_16x16x32_bf16(a, b0, acc0, 0, 0, 0);
            acc1 = __builtin_amdgcn_mfma_f32_16x16x32_bf16(a, b1v, acc1, 0, 0, 0);
        }

        // C/D layout: col = lane&15 (=r), row = (lane>>4)*4 + rr
        float* out = partial + ((size_t)ks * NN + m0 + kq * 4) * 32;
#pragma unroll
        for (int rr = 0; rr < 4; ++rr) {
            out[rr * 32 + r]      = acc0[rr];
            out[rr * 32 + 16 + r] = acc1[rr];
        }
        return;
    }

    // ---------------- scan body: one row, 128 threads ----------------
    const int sb  = bid - PGB;            // 0..8191
    const int br  = sb >> 12;             // 0..1
    const int row = sb & (NN - 1);
    const float* L   = br ? Lu : Ld;
    const float* xwB = br ? xwB2 : xwB1;
    const float* xwA = br ? xwA2 : xwA1;
    const float* aA  = br ? a2 : a1;
    const float* bA  = br ? b2 : b1;
    int2* csrB = csrv + ((size_t)br * NN + row) * CAP;
    float* u   = br ? u2 : u1;

    if (t == 0) lcnt = 0;

    // stage the whole 16 KB row into LDS: 8 global_load_lds_dwordx4 per lane,
    // fire-and-forget (no VGPR writeback). LDS dest: wave-uniform base
    // (j*128 + w*64 float4s) + lane*16 -- linear, matches the load order.
    const float4* L4 = (const float4*)(L + (size_t)row * NN);
#pragma unroll
    for (int j = 0; j < 8; ++j) {
        GLOAD_LDS16(L4 + j * 128 + t, (char*)lrow + (j * 128 + w * 64) * 16);
    }
    asm volatile("s_waitcnt vmcnt(0)" ::: "memory");
    __syncthreads();   // row + lcnt visible to the whole block

    // single-pass atomic compaction from LDS (order-invariant consumers)
#pragma unroll
    for (int j = 0; j < 8; ++j) {
        const float4 v = lrow[j * 128 + t];
        const int c0 = (j * 128 + t) * 4;
        if (v.x != 0.f) { const int s = atomicAdd(&lcnt, 1); if (s < CAP) { sidx[s] = c0;     sval[s] = v.x; } }
        if (v.y != 0.f) { const int s = atomicAdd(&lcnt, 1); if (s < CAP) { sidx[s] = c0 + 1; sval[s] = v.y; } }
        if (v.z != 0.f) { const int s = atomicAdd(&lcnt, 1); if (s < CAP) { sidx[s] = c0 + 2; sval[s] = v.z; } }
        if (v.w != 0.f) { const int s = atomicAdd(&lcnt, 1); if (s < CAP) { sidx[s] = c0 + 3; sval[s] = v.w; } }
    }
    __syncthreads();

    const int cnt  = min(lcnt, CAP);
    const int cp32 = min((cnt + 31) & ~31, CAP);   // 32-padding (accum matches)
    // sentinel fill: thread t fills its OWN slot t (published by the barrier
    // below, which precedes all cross-thread reads of these slots).
    if (t >= cnt && t < cp32) { sidx[t] = 0; sval[t] = 0.f; }

    // --- softmax over the list: thread t handles slot t ---
    const float ai = aA[row];
    const int myidx = (t < cp32) ? sidx[t] : 0;
    const float e = (t < cnt) ? lrelu(ai + bA[myidx]) : -1e30f;
    float m = e;
#pragma unroll
    for (int mm = 1; mm <= 32; mm <<= 1) m = fmaxf(m, __shfl_xor(m, mm));
    if (lane == 0) rpart[w] = m;
    __syncthreads();                               // also publishes sentinels
    m = fmaxf(rpart[0], rpart[1]);
    const float wgt = (t < cnt) ? __expf(e - m) : 0.f;
    float ss = wgt;
#pragma unroll
    for (int mm = 1; mm <= 32; mm <<= 1) ss += __shfl_xor(ss, mm);
    if (lane == 0) rpart[2 + w] = ss;
    __syncthreads();
    const float ssum = rpart[2] + rpart[3];
    const float inv = (cnt > 0) ? 1.f / ssum : 0.f;
    if (t < cp32) { int2 eo; eo.x = myidx; eo.y = __float_as_int(wgt * inv); csrB[t] = eo; }
    if (t == 0) cntArr[br * NN + row] = cnt;

    // --- fused y-gather: 32-slot chunks, 8 loads in flight per thread ---
    const int o = t & 31, g = t >> 5;      // g in 0..3
    float acc = 0.f;
    for (int s0 = 0; s0 < cp32; s0 += 32) {
        float vv[8], uu[8];
#pragma unroll
        for (int q = 0; q < 8; ++q) {
            const int sl = s0 + 4 * q + g;
            vv[q] = sval[sl];
            uu[q] = xwB[(size_t)sidx[sl] * 32 + o];
        }
#pragma unroll
        for (int q = 0; q < 8; ++q) acc += vv[q] * uu[q];
    }
    red[t] = acc;
    __syncthreads();
    if (t < 32) {
        const float tot2 = red[t] + red[32 + t] + red[64 + t] + red[96 + t];
        u[(size_t)row * 32 + t] = tot2 + xwA[(size_t)row * 32 + t];
    }
}

// ---------------------------------------------------------------------------
// K3 (k_accum2): SPLIT one level vs r9 -- wave per (row, BRANCH), 2048
// blocks x 4 waves = 8192 waves (2x parallelism, half the per-wave gather
// chain). Waves (0,1) = row r0 branches (0,1); waves (2,3) = row r1.
// Per wave: stage its branch's csrv slots (coalesced, wave-private LDS),
// 16-slot-chunk gather of U (8 loads in flight). Branch pair combined via
// LDS after one barrier; KS-partial fold runs in the writing waves only,
// hoisted first so its 8 streamed loads overlap the staging.
// ---------------------------------------------------------------------------
__global__ __launch_bounds__(256) void k_accum2(
    const int2* __restrict__ csrv, const int* __restrict__ cntArr,
    const float* __restrict__ u1, const float* __restrict__ u2,
    const float* __restrict__ partial, float* __restrict__ outp)
{
    __shared__ int2  sle[4][CAP];
    __shared__ float sacc[4][32];
    const int w = threadIdx.x >> 6, lane = threadIdx.x & 63;
    const int row = blockIdx.x * 2 + (w >> 1);
    const int br  = w & 1;
    const int o = lane & 31, g = lane >> 5;
    int2* se = sle[w];
    const float* U = br ? u2 : u1;

    // KS-partial fold in the writing waves (br==0), issued before staging so
    // the 8 coalesced loads overlap the csrv stage + gather chains.
    float ptot = 0.f;
    if (br == 0) {
#pragma unroll
        for (int p = 0; p < KS; ++p)
            ptot += partial[(size_t)p * NN * 32 + (size_t)row * 32 + o];
    }

    const int cnt = cntArr[br * NN + row];
    const int cp  = min((cnt + 31) & ~31, CAP);   // 32-padding (scan matches)
    const int2* ci = csrv + ((size_t)br * NN + row) * CAP;
    if (lane < cp)      se[lane]      = ci[lane];
    if (lane + 64 < cp) se[lane + 64] = ci[lane + 64];
    // wave-private LDS segment; same-wave ordering

    float acc = 0.f;
    const int nb = cp >> 4;                  // 16-slot chunks
    for (int j = 0; j < nb; ++j) {
        float wv[8], uv[8];
#pragma unroll
        for (int q = 0; q < 8; ++q) {
            const int2 e = se[16 * j + 2 * q + g];
            wv[q] = __int_as_float(e.y);
            uv[q] = U[(size_t)e.x * 32 + o];
        }
#pragma unroll
        for (int q = 0; q < 8; ++q) acc += wv[q] * uv[q];
    }
    acc += __shfl_xor(acc, 32);              // fold even/odd slot halves
    if (lane < 32) sacc[w][o] = acc;
    __syncthreads();

    if (br == 0 && lane < 32)
        outp[(size_t)row * 32 + o] = ptot + sacc[w][o] + sacc[w + 1][o];
}

extern "C" void kernel_launch(void* const* d_in, const int* in_sizes, int n_in,
                              void* d_out, int out_size, void* d_ws, size_t ws_size,
                              hipStream_t stream) {
    (void)in_sizes; (void)n_in; (void)out_size; (void)ws_size;
    const float* x    = (const float*)d_in[0];
    const float* Ld   = (const float*)d_in[1];
    const float* Lu   = (const float*)d_in[2];
    const float* P    = (const float*)d_in[3];
    const float* W1   = (const float*)d_in[4];
    const float* W2   = (const float*)d_in[5];
    const float* W0   = (const float*)d_in[6];
    const float* att1 = (const float*)d_in[7];
    const float* att2 = (const float*)d_in[8];

    float* ws = (float*)d_ws;
    float* xwA1 = ws;                 // 131072 each
    float* xwB1 = ws + 131072;
    float* xwA2 = ws + 262144;
    float* xwB2 = ws + 393216;
    float* u1   = ws + 524288;        // xwA + L@xwB (fused)
    float* u2   = ws + 655360;
    float* a1   = ws + 786432;        // 4096 each
    float* b1   = ws + 790528;
    float* a2   = ws + 794624;
    float* b2   = ws + 798720;
    float* partial = ws + 802816;           // KS*131072 floats = 4 MB
    __hip_bfloat16* Bt = (__hip_bfloat16*)(ws + 1851392);   // 131072 bf16
    int2* csrv = (int2*)(ws + 1916928);     // 2*4096*128 int2 = 8 MB
    int*  cnt  = (int*)(ws + 4014080);      // 8192 ints

    k_prep<<<512, 256, 0, stream>>>(x, W1, W2, W0, att1, att2,
                                    xwA1, xwB1, xwA2, xwB2, a1, b1, a2, b2, Bt);
    k_fused<<<PGB + 2 * NN, 128, 0, stream>>>(Ld, Lu, xwB1, xwB2, xwA1, xwA2,
                                              a1, b1, a2, b2, csrv, cnt, u1, u2,
                                              P, (const ushort*)Bt, partial);
    k_accum2<<<NN / 2, 256, 0, stream>>>(csrv, cnt, u1, u2, partial,
                                         (float*)d_out);
}